// Round 8
// baseline (34.118 us; speedup 1.0000x reference)
//
#include <hip/hip_runtime.h>
#include <cstdint>
#include <cstddef>

typedef _Float16 half8 __attribute__((ext_vector_type(8)));
typedef float f32x4 __attribute__((ext_vector_type(4)));

static constexpr int kN  = 256;          // state dim (N == K)
static constexpr int kKS = 8;            // k-steps of 32
static constexpr int kNT = 16;           // n-tiles of 16
static constexpr int kBM = 64;           // rows per block (4 waves x 16)

// Pack A_stacked[t] (fp32 row-major [n][k]) into f16 MFMA B-fragment order:
// a16[((nt*8 + ks)*64 + l)*8 + j] = A[nt*16 + (l&15)][ks*32 + (l>>4)*8 + j]
__global__ __launch_bounds__(256) void hippo_prep(
    const float* __restrict__ A_stacked, const int* __restrict__ tptr,
    _Float16* __restrict__ a16)
{
    const int t = tptr[0];
    const float* __restrict__ A = A_stacked + (size_t)t * kN * kN;
    const int tid = blockIdx.x * 256 + threadIdx.x;   // 0..8191
    const int nt = tid >> 9;
    const int ks = (tid >> 6) & 7;
    const int l  = tid & 63;
    const int row = nt * 16 + (l & 15);
    const int k0  = ks * 32 + ((l >> 4) << 3);
    const float* __restrict__ src = A + row * kN + k0;
    f32x4 v0 = *(const f32x4*)(src);
    f32x4 v1 = *(const f32x4*)(src + 4);
    half8 h;
    h[0] = (_Float16)v0[0]; h[1] = (_Float16)v0[1];
    h[2] = (_Float16)v0[2]; h[3] = (_Float16)v0[3];
    h[4] = (_Float16)v1[0]; h[5] = (_Float16)v1[1];
    h[6] = (_Float16)v1[2]; h[7] = (_Float16)v1[3];
    ((half8*)a16)[tid] = h;
}

// out[m][n] = sum_k c[m][k] * A_t[n][k] + b[n] * f[m]
// NO LDS, NO barrier: B-frags read from L2-resident a16 directly into regs.
// 4 waves/block (independent), grid 512 -> ~12 waves/CU of unsynchronized
// work; wave TLP + compiler vmcnt overlap HBM reads, L1/L2 B-reads, MFMA,
// and stores with no drain points.
__global__ __launch_bounds__(256, 3) void hippo_gemm(
    const float* __restrict__ c, const float* __restrict__ f,
    const float* __restrict__ Bst, const int* __restrict__ tptr,
    const _Float16* __restrict__ a16, float* __restrict__ out)
{
    const int tid  = threadIdx.x;
    const int l    = tid & 63;
    const int wid  = tid >> 6;          // 0..3
    const int lo16 = l & 15;
    const int hi4  = l >> 4;
    const int m0   = blockIdx.x * kBM + wid * 16;

    // ---- c loads, first half (ks 0..3): deepest latency, issue first ----
    const float* __restrict__ cptr = c + (size_t)(m0 + lo16) * kN + (hi4 << 3);
    f32x4 cv0[4], cv1[4];
    #pragma unroll
    for (int ks = 0; ks < 4; ++ks) {
        cv0[ks] = *(const f32x4*)(cptr + ks * 32);
        cv1[ks] = *(const f32x4*)(cptr + ks * 32 + 4);
    }

    // ---- bias loads (L2/L3, small) ----
    const int t = tptr[0];
    const float* __restrict__ brow = Bst + (size_t)t * kN;
    float bvs[kNT];
    #pragma unroll
    for (int nt = 0; nt < kNT; ++nt) bvs[nt] = brow[nt * 16 + lo16];
    float fv[4];
    #pragma unroll
    for (int r = 0; r < 4; ++r) fv[r] = f[m0 + (hi4 << 2) + r];

    const half8* __restrict__ Bg = (const half8*)a16;
    f32x4 acc[kNT];
    #pragma unroll
    for (int i = 0; i < kNT; ++i) acc[i] = (f32x4){0.f, 0.f, 0.f, 0.f};

    // ---- phase 1: ks 0..3, bf streamed from L1/L2 ----
    f32x4 dv0[4], dv1[4];   // second-half c, issued under ks-0 compute
    #pragma unroll
    for (int ks = 0; ks < 4; ++ks) {
        half8 af;
        af[0] = (_Float16)cv0[ks][0]; af[1] = (_Float16)cv0[ks][1];
        af[2] = (_Float16)cv0[ks][2]; af[3] = (_Float16)cv0[ks][3];
        af[4] = (_Float16)cv1[ks][0]; af[5] = (_Float16)cv1[ks][1];
        af[6] = (_Float16)cv1[ks][2]; af[7] = (_Float16)cv1[ks][3];
        #pragma unroll
        for (int nt = 0; nt < kNT; ++nt) {
            half8 bf = Bg[(nt * kKS + ks) * 64 + l];
            acc[nt] = __builtin_amdgcn_mfma_f32_16x16x32_f16(af, bf, acc[nt], 0, 0, 0);
        }
        if (ks == 0) {
            #pragma unroll
            for (int j = 0; j < 4; ++j) {
                dv0[j] = *(const f32x4*)(cptr + (4 + j) * 32);
                dv1[j] = *(const f32x4*)(cptr + (4 + j) * 32 + 4);
            }
        }
    }

    // ---- phase 2: ks 4..6 ----
    half8 af2[4];
    #pragma unroll
    for (int j = 0; j < 4; ++j) {
        af2[j][0] = (_Float16)dv0[j][0]; af2[j][1] = (_Float16)dv0[j][1];
        af2[j][2] = (_Float16)dv0[j][2]; af2[j][3] = (_Float16)dv0[j][3];
        af2[j][4] = (_Float16)dv1[j][0]; af2[j][5] = (_Float16)dv1[j][1];
        af2[j][6] = (_Float16)dv1[j][2]; af2[j][7] = (_Float16)dv1[j][3];
    }
    #pragma unroll
    for (int j = 0; j < 3; ++j) {
        #pragma unroll
        for (int nt = 0; nt < kNT; ++nt) {
            half8 bf = Bg[(nt * kKS + 4 + j) * 64 + l];
            acc[nt] = __builtin_amdgcn_mfma_f32_16x16x32_f16(af2[j], bf, acc[nt], 0, 0, 0);
        }
    }

    // ---- phase 3: ks 7 fused with streamed stores ----
    float* __restrict__ obase = out + (size_t)(m0 + (hi4 << 2)) * kN + lo16;
    #pragma unroll
    for (int nt = 0; nt < kNT; nt += 2) {
        half8 bf0 = Bg[(nt * kKS + 7) * 64 + l];
        half8 bf1 = Bg[((nt + 1) * kKS + 7) * 64 + l];
        acc[nt]     = __builtin_amdgcn_mfma_f32_16x16x32_f16(af2[3], bf0, acc[nt], 0, 0, 0);
        acc[nt + 1] = __builtin_amdgcn_mfma_f32_16x16x32_f16(af2[3], bf1, acc[nt + 1], 0, 0, 0);
        #pragma unroll
        for (int r = 0; r < 4; ++r) {
            obase[(size_t)r * kN + nt * 16]       = acc[nt][r]     + bvs[nt] * fv[r];
            obase[(size_t)r * kN + (nt + 1) * 16] = acc[nt + 1][r] + bvs[nt + 1] * fv[r];
        }
    }
}

extern "C" void kernel_launch(void* const* d_in, const int* in_sizes, int n_in,
                              void* d_out, int out_size, void* d_ws, size_t ws_size,
                              hipStream_t stream) {
    const float* c   = (const float*)d_in[0];
    const float* f   = (const float*)d_in[1];
    const float* A   = (const float*)d_in[2];
    const float* B   = (const float*)d_in[3];
    const int*   t   = (const int*)d_in[4];
    float* out = (float*)d_out;
    _Float16* a16 = (_Float16*)d_ws;   // 128 KiB packed A[t] f16

    const int batch = in_sizes[0] / kN;   // 32768

    hipLaunchKernelGGL(hippo_prep, dim3(32), dim3(256), 0, stream, A, t, a16);
    hipLaunchKernelGGL(hippo_gemm, dim3(batch / kBM), dim3(256), 0, stream,
                       c, f, B, t, a16, out);
}

// Round 9
// 25.768 us; speedup vs baseline: 1.3240x; 1.3240x over previous
//
#include <hip/hip_runtime.h>
#include <cstdint>
#include <cstddef>

typedef _Float16 half8 __attribute__((ext_vector_type(8)));
typedef float f32x4 __attribute__((ext_vector_type(4)));

static constexpr int kN  = 256;          // state dim (N == K)
static constexpr int kKS = 8;            // k-steps of 32
static constexpr int kBM = 128;          // rows per block (4 m-waves x 32)
static constexpr size_t kABytes = (size_t)kN * kN * 2;  // 128 KiB packed f16 A

// Pack A_stacked[t] (fp32 row-major [n][k]) into f16 MFMA B-fragment order:
// a16[((NT*8 + ks)*64 + l)*8 + j] = A[NT*16 + (l&15)][ks*32 + (l>>4)*8 + j]
__global__ __launch_bounds__(256) void hippo_prep(
    const float* __restrict__ A_stacked, const int* __restrict__ tptr,
    _Float16* __restrict__ a16)
{
    const int t = tptr[0];
    const float* __restrict__ A = A_stacked + (size_t)t * kN * kN;
    const int tid = blockIdx.x * 256 + threadIdx.x;   // 0..8191
    const int nt = tid >> 9;
    const int ks = (tid >> 6) & 7;
    const int l  = tid & 63;
    const int row = nt * 16 + (l & 15);
    const int k0  = ks * 32 + ((l >> 4) << 3);
    const float* __restrict__ src = A + row * kN + k0;
    f32x4 v0 = *(const f32x4*)(src);
    f32x4 v1 = *(const f32x4*)(src + 4);
    half8 h;
    h[0] = (_Float16)v0[0]; h[1] = (_Float16)v0[1];
    h[2] = (_Float16)v0[2]; h[3] = (_Float16)v0[3];
    h[4] = (_Float16)v1[0]; h[5] = (_Float16)v1[1];
    h[6] = (_Float16)v1[2]; h[7] = (_Float16)v1[3];
    ((half8*)a16)[tid] = h;
}

// out[m][n] = sum_k c[m][k] * A_t[n][k] + b[n] * f[m]
// 8 waves as 4m x 2n: wave (wm, wn) owns rows [wm*32,+32) x cols [wn*128,+128).
// Each wave reads only its 8 n-tiles from LDS (64 KB, half of R7) and reuses
// each bf across 2 m-subtiles. c loaded post-barrier in two ks-halves.
__global__ __launch_bounds__(512, 2) void hippo_gemm(
    const float* __restrict__ c, const float* __restrict__ f,
    const float* __restrict__ Bst, const int* __restrict__ tptr,
    const _Float16* __restrict__ a16, float* __restrict__ out)
{
    extern __shared__ char lds_raw[];

    const int tid  = threadIdx.x;
    const int l    = tid & 63;
    const int wid  = tid >> 6;          // 0..7
    const int wm   = wid & 3;           // m-tile 0..3 (32 rows each)
    const int wn   = wid >> 2;          // n-half 0..1 (128 cols each)
    const int lo16 = l & 15;
    const int hi4  = l >> 4;
    const int m0   = blockIdx.x * kBM + wm * 32;
    const int ntb  = wn * 8;            // this wave's first global n-tile

    // ---- DMA-stage packed A (128 KiB) into LDS; nothing else outstanding ----
    #pragma unroll
    for (int i = 0; i < 16; ++i) {
        const int chunk = i * 8 + wid;                 // 0..127, 1 KiB each
        const size_t off = (size_t)chunk * 1024 + (size_t)l * 16;
        __builtin_amdgcn_global_load_lds(
            (const __attribute__((address_space(1))) void*)((const char*)a16 + off),
            (__attribute__((address_space(3))) void*)(lds_raw + off),
            16, 0, 0);
    }
    __syncthreads();   // drains only the A-DMA (L2-fed)

    // ---- post-barrier: c loads ks 0..3, both m-subtiles ----
    const float* __restrict__ cptr0 = c + (size_t)(m0 + lo16) * kN + (hi4 << 3);
    const float* __restrict__ cptr1 = cptr0 + (size_t)16 * kN;
    f32x4 cA0[4], cA1[4], cB0[4], cB1[4];
    #pragma unroll
    for (int ks = 0; ks < 4; ++ks) {
        cA0[ks] = *(const f32x4*)(cptr0 + ks * 32);
        cA1[ks] = *(const f32x4*)(cptr0 + ks * 32 + 4);
        cB0[ks] = *(const f32x4*)(cptr1 + ks * 32);
        cB1[ks] = *(const f32x4*)(cptr1 + ks * 32 + 4);
    }

    // ---- bias loads (small, L2) ----
    const int t = tptr[0];
    const float* __restrict__ brow = Bst + (size_t)t * kN + wn * 128;
    float bvs[8];
    #pragma unroll
    for (int nt = 0; nt < 8; ++nt) bvs[nt] = brow[nt * 16 + lo16];
    float fv0[4], fv1[4];
    #pragma unroll
    for (int r = 0; r < 4; ++r) {
        fv0[r] = f[m0 + (hi4 << 2) + r];
        fv1[r] = f[m0 + 16 + (hi4 << 2) + r];
    }

    // ---- cvt ks 0..3 -> f16 frags; then issue ks 4..7 c loads ----
    half8 afA[4], afB[4];
    #pragma unroll
    for (int ks = 0; ks < 4; ++ks) {
        afA[ks][0] = (_Float16)cA0[ks][0]; afA[ks][1] = (_Float16)cA0[ks][1];
        afA[ks][2] = (_Float16)cA0[ks][2]; afA[ks][3] = (_Float16)cA0[ks][3];
        afA[ks][4] = (_Float16)cA1[ks][0]; afA[ks][5] = (_Float16)cA1[ks][1];
        afA[ks][6] = (_Float16)cA1[ks][2]; afA[ks][7] = (_Float16)cA1[ks][3];
        afB[ks][0] = (_Float16)cB0[ks][0]; afB[ks][1] = (_Float16)cB0[ks][1];
        afB[ks][2] = (_Float16)cB0[ks][2]; afB[ks][3] = (_Float16)cB0[ks][3];
        afB[ks][4] = (_Float16)cB1[ks][0]; afB[ks][5] = (_Float16)cB1[ks][1];
        afB[ks][6] = (_Float16)cB1[ks][2]; afB[ks][7] = (_Float16)cB1[ks][3];
    }
    f32x4 dA0[4], dA1[4], dB0[4], dB1[4];   // ks 4..7, latency hides under phase 1
    #pragma unroll
    for (int j = 0; j < 4; ++j) {
        dA0[j] = *(const f32x4*)(cptr0 + (4 + j) * 32);
        dA1[j] = *(const f32x4*)(cptr0 + (4 + j) * 32 + 4);
        dB0[j] = *(const f32x4*)(cptr1 + (4 + j) * 32);
        dB1[j] = *(const f32x4*)(cptr1 + (4 + j) * 32 + 4);
    }

    // ---- phase 1: ks 0..3, each bf reused by both m-subtiles ----
    const half8* __restrict__ Bs = (const half8*)lds_raw;
    f32x4 accA[8], accB[8];
    #pragma unroll
    for (int i = 0; i < 8; ++i) {
        accA[i] = (f32x4){0.f, 0.f, 0.f, 0.f};
        accB[i] = (f32x4){0.f, 0.f, 0.f, 0.f};
    }
    #pragma unroll
    for (int ks = 0; ks < 4; ++ks) {
        #pragma unroll
        for (int nt = 0; nt < 8; ++nt) {
            half8 bf = Bs[((ntb + nt) * kKS + ks) * 64 + l];
            accA[nt] = __builtin_amdgcn_mfma_f32_16x16x32_f16(afA[ks], bf, accA[nt], 0, 0, 0);
            accB[nt] = __builtin_amdgcn_mfma_f32_16x16x32_f16(afB[ks], bf, accB[nt], 0, 0, 0);
        }
    }

    // ---- cvt ks 4..7 ----
    half8 agA[4], agB[4];
    #pragma unroll
    for (int j = 0; j < 4; ++j) {
        agA[j][0] = (_Float16)dA0[j][0]; agA[j][1] = (_Float16)dA0[j][1];
        agA[j][2] = (_Float16)dA0[j][2]; agA[j][3] = (_Float16)dA0[j][3];
        agA[j][4] = (_Float16)dA1[j][0]; agA[j][5] = (_Float16)dA1[j][1];
        agA[j][6] = (_Float16)dA1[j][2]; agA[j][7] = (_Float16)dA1[j][3];
        agB[j][0] = (_Float16)dB0[j][0]; agB[j][1] = (_Float16)dB0[j][1];
        agB[j][2] = (_Float16)dB0[j][2]; agB[j][3] = (_Float16)dB0[j][3];
        agB[j][4] = (_Float16)dB1[j][0]; agB[j][5] = (_Float16)dB1[j][1];
        agB[j][6] = (_Float16)dB1[j][2]; agB[j][7] = (_Float16)dB1[j][3];
    }

    // ---- phase 2: ks 4..6 ----
    #pragma unroll
    for (int j = 0; j < 3; ++j) {
        #pragma unroll
        for (int nt = 0; nt < 8; ++nt) {
            half8 bf = Bs[((ntb + nt) * kKS + 4 + j) * 64 + l];
            accA[nt] = __builtin_amdgcn_mfma_f32_16x16x32_f16(agA[j], bf, accA[nt], 0, 0, 0);
            accB[nt] = __builtin_amdgcn_mfma_f32_16x16x32_f16(agB[j], bf, accB[nt], 0, 0, 0);
        }
    }

    // ---- phase 3: ks 7 fused with streamed stores ----
    float* __restrict__ oA = out + (size_t)(m0 + (hi4 << 2)) * kN + wn * 128 + lo16;
    float* __restrict__ oB = oA + (size_t)16 * kN;
    #pragma unroll
    for (int nt = 0; nt < 8; ++nt) {
        half8 bf = Bs[((ntb + nt) * kKS + 7) * 64 + l];
        accA[nt] = __builtin_amdgcn_mfma_f32_16x16x32_f16(agA[3], bf, accA[nt], 0, 0, 0);
        accB[nt] = __builtin_amdgcn_mfma_f32_16x16x32_f16(agB[3], bf, accB[nt], 0, 0, 0);
        #pragma unroll
        for (int r = 0; r < 4; ++r) {
            oA[(size_t)r * kN + nt * 16] = accA[nt][r] + bvs[nt] * fv0[r];
            oB[(size_t)r * kN + nt * 16] = accB[nt][r] + bvs[nt] * fv1[r];
        }
    }
}

extern "C" void kernel_launch(void* const* d_in, const int* in_sizes, int n_in,
                              void* d_out, int out_size, void* d_ws, size_t ws_size,
                              hipStream_t stream) {
    const float* c   = (const float*)d_in[0];
    const float* f   = (const float*)d_in[1];
    const float* A   = (const float*)d_in[2];
    const float* B   = (const float*)d_in[3];
    const int*   t   = (const int*)d_in[4];
    float* out = (float*)d_out;
    _Float16* a16 = (_Float16*)d_ws;   // 128 KiB packed A[t] f16

    const int batch = in_sizes[0] / kN;   // 32768

    hipFuncSetAttribute((const void*)hippo_gemm,
                        hipFuncAttributeMaxDynamicSharedMemorySize,
                        (int)kABytes);

    hipLaunchKernelGGL(hippo_prep, dim3(32), dim3(256), 0, stream, A, t, a16);
    hipLaunchKernelGGL(hippo_gemm, dim3(batch / kBM), dim3(512), kABytes, stream,
                       c, f, B, t, a16, out);
}

// Round 10
// 22.866 us; speedup vs baseline: 1.4921x; 1.1269x over previous
//
#include <hip/hip_runtime.h>
#include <cstdint>
#include <cstddef>

typedef _Float16 half8 __attribute__((ext_vector_type(8)));
typedef float f32x4 __attribute__((ext_vector_type(4)));

static constexpr int kN  = 256;            // state dim (N == K)
static constexpr int kBM = 64;             // rows per block (4 waves x 16)
static constexpr size_t kHalfB  = 64 * 1024;   // one ks-half of packed B
static constexpr size_t kLDS    = kHalfB;      // 64 KiB -> 2 blocks/CU

// Pack A_stacked[t] (fp32 [n][k]) into f16 frag order, ks-half outermost:
// a16[ ((ksh*16 + nt)*4 + ks2)*64 + l ] (half8 units)
//   = A[nt*16 + (l&15)][ (ksh*4 + ks2)*32 + (l>>4)*8 + j ]
__global__ __launch_bounds__(256) void hippo_prep(
    const float* __restrict__ A_stacked, const int* __restrict__ tptr,
    _Float16* __restrict__ a16)
{
    const int t = tptr[0];
    const float* __restrict__ A = A_stacked + (size_t)t * kN * kN;
    const int tid = blockIdx.x * 256 + threadIdx.x;   // 0..8191
    const int ksh = tid >> 12;
    const int nt  = (tid >> 8) & 15;
    const int ks2 = (tid >> 6) & 3;
    const int l   = tid & 63;
    const int row = nt * 16 + (l & 15);
    const int k0  = (ksh * 4 + ks2) * 32 + ((l >> 4) << 3);
    const float* __restrict__ src = A + (size_t)row * kN + k0;
    f32x4 v0 = *(const f32x4*)(src);
    f32x4 v1 = *(const f32x4*)(src + 4);
    half8 h;
    h[0] = (_Float16)v0[0]; h[1] = (_Float16)v0[1];
    h[2] = (_Float16)v0[2]; h[3] = (_Float16)v0[3];
    h[4] = (_Float16)v1[0]; h[5] = (_Float16)v1[1];
    h[6] = (_Float16)v1[2]; h[7] = (_Float16)v1[3];
    ((half8*)a16)[tid] = h;
}

// out[m][n] = sum_k c[m][k] * A_t[n][k] + b[n] * f[m]
// 4-wave blocks, 64 KiB LDS (one ks-half of B at a time, overwritten mid-
// kernel) -> 2 co-resident blocks/CU. Each block processes its two ks-halves
// in parity-dependent order; partner block fills this block's stall phases.
__global__ __launch_bounds__(256, 2) void hippo_gemm(
    const float* __restrict__ c, const float* __restrict__ f,
    const float* __restrict__ Bst, const int* __restrict__ tptr,
    const _Float16* __restrict__ a16, float* __restrict__ out)
{
    extern __shared__ char lds_raw[];

    const int tid  = threadIdx.x;
    const int l    = tid & 63;
    const int wid  = tid >> 6;          // 0..3
    const int lo16 = l & 15;
    const int hi4  = l >> 4;
    const int bid  = blockIdx.x;
    const int m0   = bid * kBM + wid * 16;
    const int hA   = bid & 1;           // first ks-half (parity-staggered)
    const int hB   = hA ^ 1;

    // ---- DMA half hA into LDS (64 chunks of 1 KiB across 4 waves) ----
    const char* __restrict__ gsrcA = (const char*)a16 + (size_t)hA * kHalfB;
    #pragma unroll
    for (int i = 0; i < 16; ++i) {
        const size_t off = (size_t)(i * 4 + wid) * 1024 + (size_t)l * 16;
        __builtin_amdgcn_global_load_lds(
            (const __attribute__((address_space(1))) void*)(gsrcA + off),
            (__attribute__((address_space(3))) void*)(lds_raw + off),
            16, 0, 0);
    }

    // ---- c loads for half hA (k = hA*128 .. +128) ----
    const float* __restrict__ cptr = c + (size_t)(m0 + lo16) * kN + (hi4 << 3);
    f32x4 cv0[4], cv1[4];
    #pragma unroll
    for (int ks = 0; ks < 4; ++ks) {
        cv0[ks] = *(const f32x4*)(cptr + hA * 128 + ks * 32);
        cv1[ks] = *(const f32x4*)(cptr + hA * 128 + ks * 32 + 4);
    }

    // ---- bias loads ----
    const int t = tptr[0];
    const float* __restrict__ brow = Bst + (size_t)t * kN;
    float bvs[16];
    #pragma unroll
    for (int nt = 0; nt < 16; ++nt) bvs[nt] = brow[nt * 16 + lo16];
    float fv[4];
    #pragma unroll
    for (int r = 0; r < 4; ++r) fv[r] = f[m0 + (hi4 << 2) + r];

    __syncthreads();   // drains DMA(hA) + c(hA); partner block overlaps

    // ---- cvt + compute half hA ----
    half8 af[4];
    #pragma unroll
    for (int ks = 0; ks < 4; ++ks) {
        af[ks][0] = (_Float16)cv0[ks][0]; af[ks][1] = (_Float16)cv0[ks][1];
        af[ks][2] = (_Float16)cv0[ks][2]; af[ks][3] = (_Float16)cv0[ks][3];
        af[ks][4] = (_Float16)cv1[ks][0]; af[ks][5] = (_Float16)cv1[ks][1];
        af[ks][6] = (_Float16)cv1[ks][2]; af[ks][7] = (_Float16)cv1[ks][3];
    }
    const half8* __restrict__ Bs = (const half8*)lds_raw;
    f32x4 acc[16];
    #pragma unroll
    for (int i = 0; i < 16; ++i) acc[i] = (f32x4){0.f, 0.f, 0.f, 0.f};
    #pragma unroll
    for (int ks = 0; ks < 4; ++ks) {
        #pragma unroll
        for (int nt = 0; nt < 16; ++nt) {
            half8 bf = Bs[(nt * 4 + ks) * 64 + l];
            acc[nt] = __builtin_amdgcn_mfma_f32_16x16x32_f16(af[ks], bf, acc[nt], 0, 0, 0);
        }
    }

    __syncthreads();   // all LDS reads of half hA complete -> safe to overwrite

    // ---- DMA half hB + c loads for half hB ----
    const char* __restrict__ gsrcB = (const char*)a16 + (size_t)hB * kHalfB;
    #pragma unroll
    for (int i = 0; i < 16; ++i) {
        const size_t off = (size_t)(i * 4 + wid) * 1024 + (size_t)l * 16;
        __builtin_amdgcn_global_load_lds(
            (const __attribute__((address_space(1))) void*)(gsrcB + off),
            (__attribute__((address_space(3))) void*)(lds_raw + off),
            16, 0, 0);
    }
    f32x4 dv0[4], dv1[4];
    #pragma unroll
    for (int ks = 0; ks < 4; ++ks) {
        dv0[ks] = *(const f32x4*)(cptr + hB * 128 + ks * 32);
        dv1[ks] = *(const f32x4*)(cptr + hB * 128 + ks * 32 + 4);
    }

    __syncthreads();   // drains DMA(hB) + c(hB)

    // ---- cvt + compute half hB ----
    half8 ag[4];
    #pragma unroll
    for (int ks = 0; ks < 4; ++ks) {
        ag[ks][0] = (_Float16)dv0[ks][0]; ag[ks][1] = (_Float16)dv0[ks][1];
        ag[ks][2] = (_Float16)dv0[ks][2]; ag[ks][3] = (_Float16)dv0[ks][3];
        ag[ks][4] = (_Float16)dv1[ks][0]; ag[ks][5] = (_Float16)dv1[ks][1];
        ag[ks][6] = (_Float16)dv1[ks][2]; ag[ks][7] = (_Float16)dv1[ks][3];
    }
    #pragma unroll
    for (int ks = 0; ks < 4; ++ks) {
        #pragma unroll
        for (int nt = 0; nt < 16; ++nt) {
            half8 bf = Bs[(nt * 4 + ks) * 64 + l];
            acc[nt] = __builtin_amdgcn_mfma_f32_16x16x32_f16(ag[ks], bf, acc[nt], 0, 0, 0);
        }
    }

    // ---- epilogue ----
    float* __restrict__ obase = out + (size_t)(m0 + (hi4 << 2)) * kN + lo16;
    #pragma unroll
    for (int nt = 0; nt < 16; ++nt) {
        #pragma unroll
        for (int r = 0; r < 4; ++r)
            obase[(size_t)r * kN + nt * 16] = acc[nt][r] + bvs[nt] * fv[r];
    }
}

extern "C" void kernel_launch(void* const* d_in, const int* in_sizes, int n_in,
                              void* d_out, int out_size, void* d_ws, size_t ws_size,
                              hipStream_t stream) {
    const float* c   = (const float*)d_in[0];
    const float* f   = (const float*)d_in[1];
    const float* A   = (const float*)d_in[2];
    const float* B   = (const float*)d_in[3];
    const int*   t   = (const int*)d_in[4];
    float* out = (float*)d_out;
    _Float16* a16 = (_Float16*)d_ws;   // 128 KiB packed A[t] f16, ks-half-major

    const int batch = in_sizes[0] / kN;   // 32768

    hipFuncSetAttribute((const void*)hippo_gemm,
                        hipFuncAttributeMaxDynamicSharedMemorySize,
                        (int)kLDS);

    hipLaunchKernelGGL(hippo_prep, dim3(32), dim3(256), 0, stream, A, t, a16);
    hipLaunchKernelGGL(hippo_gemm, dim3(batch / kBM), dim3(256), kLDS, stream,
                       c, f, B, t, a16, out);
}